// Round 6
// baseline (245.389 us; speedup 1.0000x reference)
//
#include <hip/hip_runtime.h>

// ContrastiveLoss on MI355X (gfx950) — round 10
// loss = (1/n) [ sum_i P_i*(10+log z_i) - 10*(sum_c ||S_c||^2 - n) ]
//   z_i = sum_{j != i} exp(10*dot_ij - 10)
//   S_c = sum_{label_j == c} e_j   (exact fp32 via rowlist gather)
// R10: (a) zsum jt-loop unroll 4 (deeper compiler prefetch pipeline) with
// __launch_bounds__(256,4) pinning <=128 VGPR / 4 waves per SIMD so the
// unroll can't trade occupancy away. (b) classsum folded into zsum's grid
// (blocks x>=32 handle 2 classes each): its latency-bound gathers co-reside
// free in the VGPR slack (4x116=464/512) and fill zsum's stall bubbles.
// ~84us of measured time is harness poison-fill (2x256MB) — immovable.

#define N 8192
#define D 128
#define NCLS 100
#define RLCAP 256          // rowlist slots per class (~82+-9 expected; huge margin)
#define JSPLIT 32          // grid.y; j-window = 256 rows
#define IBLK 256           // i-rows per block (4 waves x 64)
#define NJT ((N / JSPLIT) / 16)
#define XGRID 34           // 32 zsum block-cols + 2 cols of classsum blocks
#define K2E 14.4269504088896340736f   // 10*log2(e)
#define LN2 0.69314718055994530942f

typedef __bf16 bf16x8 __attribute__((ext_vector_type(8)));
typedef float f32x4 __attribute__((ext_vector_type(4)));

// ws layout (bytes) — CNT and Z contiguous so one memset zeroes both
#define EBF_OFF  0x000000u  // bf16 E fragment-major: 2 MB
#define ENORM_OFF 0x200000u // fp32 normalized E row-major: 4 MB
#define CNT_OFF  0x600000u  // class counts: 512 B
#define Z_OFF    0x600200u  // z per row: 32 KB
#define RL_OFF   0x608200u  // rowlist: 100*256*4 = 100 KB (gated by cnt, no init)
#define S_OFF    0x621200u  // S_c: 100*128*4 = 50 KB (fully written)
#define ZERO_SZ  (512u + 32768u)

__device__ __forceinline__ unsigned short f32_to_bf16_rne(float f) {
    unsigned int u = __float_as_uint(f);
    u += 0x7fffu + ((u >> 16) & 1u);
    return (unsigned short)(u >> 16);
}

// Fragment-major layout of E (harness-verified):
//   row r: grp=r>>4, col=r&15 ; element k: c=k>>5, q=(k>>3)&3, jj=k&7
//   byte = grp*4096 + c*1024 + q*256 + col*16 + jj*2

// Kernel 1: normalize rows -> fragment-major bf16 E + row-major fp32 enorm;
// class histogram doubles as rowlist slot allocator (1 atomic per row).
__global__ __launch_bounds__(256) void prep_kernel(
        const float* __restrict__ emb, const int* __restrict__ labels,
        unsigned char* __restrict__ ebf, int* __restrict__ cnt,
        float* __restrict__ enorm, int* __restrict__ rowlist) {
    const int wave = threadIdx.x >> 6;
    const int lane = threadIdx.x & 63;
    const int row  = blockIdx.x * 4 + wave;

    const float2 v = *(const float2*)(emb + (size_t)row * D + lane * 2);
    float ss = v.x * v.x + v.y * v.y;
    #pragma unroll
    for (int off = 32; off; off >>= 1) ss += __shfl_xor(ss, off);
    const float inv = 1.0f / fmaxf(sqrtf(ss), 1e-12f);
    const float ex = v.x * inv, ey = v.y * inv;

    const int grp = row >> 4, col = row & 15;
    const int c = lane >> 4, q = (lane >> 2) & 3, j2 = lane & 3;
    unsigned int packed = (unsigned int)f32_to_bf16_rne(ex) |
                          ((unsigned int)f32_to_bf16_rne(ey) << 16);
    *(unsigned int*)(ebf + grp * 4096 + c * 1024 + q * 256 + col * 16 + j2 * 4) = packed;

    float2* ep = (float2*)(enorm + (size_t)row * D + lane * 2);
    *ep = make_float2(ex, ey);

    if (lane == 0) {
        const int lab = labels[row];
        int slot = atomicAdd(&cnt[lab], 1);
        slot = slot < RLCAP ? slot : RLCAP - 1;   // defensive (never hit @ ~82/class)
        rowlist[lab * RLCAP + slot] = row;
    }
}

// Kernel 2: z (blocks x<32) + per-class sums (blocks x>=32, 2 classes each).
// zsum path: wave owns 64 i-rows (4 groups of 16); no LDS, no barriers;
// B register-double-buffered, jt unroll 4 for deep load pipelining.
__global__ __launch_bounds__(256, 4) void zsum_kernel(
        const unsigned char* __restrict__ ebf, float* __restrict__ z,
        const float* __restrict__ enorm, const int* __restrict__ cnt,
        const int* __restrict__ rowlist, float* __restrict__ S) {
    const int t = threadIdx.x;

    if (blockIdx.x >= 32) {
        // ---- classsum path: block covers classes 2*eidx, 2*eidx+1 ----
        const int eidx = (blockIdx.x - 32) * JSPLIT + blockIdx.y;
        if (eidx >= (NCLS + 1) / 2) return;
        const int c = 2 * eidx + (t >> 7);
        if (c >= NCLS) return;
        const int d = t & 127;
        const int n = cnt[c] < RLCAP ? cnt[c] : RLCAP;
        const int* rl = rowlist + c * RLCAP;
        float acc = 0.0f;
        int idx = 0;
        for (; idx + 4 <= n; idx += 4) {
            const int r0 = rl[idx], r1 = rl[idx + 1], r2 = rl[idx + 2], r3 = rl[idx + 3];
            acc += enorm[(size_t)r0 * D + d] + enorm[(size_t)r1 * D + d]
                 + enorm[(size_t)r2 * D + d] + enorm[(size_t)r3 * D + d];
        }
        for (; idx < n; ++idx)
            acc += enorm[(size_t)rl[idx] * D + d];
        S[c * D + d] = acc;
        return;
    }

    // ---- zsum path ----
    const int w    = t >> 6;
    const int lane = t & 63;
    const int q    = lane >> 4;
    const int col  = lane & 15;
    const int iw   = blockIdx.x * IBLK + w * 64;
    const int jb   = blockIdx.y * (N / JSPLIT);

    // A fragments: 4 groups x 4 K-chunks, coalesced 1KB loads
    bf16x8 a[4][4];
    #pragma unroll
    for (int g = 0; g < 4; ++g) {
        const unsigned char* ag = ebf + (size_t)(iw / 16 + g) * 4096 + lane * 16;
        #pragma unroll
        for (int c = 0; c < 4; ++c) a[g][c] = *(const bf16x8*)(ag + c * 1024);
    }

    float zacc[4][4] = {{0.f,0.f,0.f,0.f},{0.f,0.f,0.f,0.f},
                        {0.f,0.f,0.f,0.f},{0.f,0.f,0.f,0.f}};

    const unsigned char* bbase = ebf + (size_t)(jb / 16) * 4096 + lane * 16;

    // prologue: load B tile 0
    bf16x8 bc[4];
    #pragma unroll
    for (int c = 0; c < 4; ++c) bc[c] = *(const bf16x8*)(bbase + c * 1024);

    #pragma unroll 4
    for (int jt = 0; jt < NJT; ++jt) {
        const int js = jb + jt * 16;

        // prefetch next B tile (last iter reloads current — harmless, defined)
        const int jn = (jt + 1 < NJT) ? jt + 1 : jt;
        bf16x8 bn[4];
        {
            const unsigned char* bg = bbase + (size_t)jn * 4096;
            #pragma unroll
            for (int c = 0; c < 4; ++c) bn[c] = *(const bf16x8*)(bg + c * 1024);
        }

        #pragma unroll
        for (int g = 0; g < 4; ++g) {
            f32x4 acc = {0.f, 0.f, 0.f, 0.f};
            __builtin_amdgcn_s_setprio(1);
            #pragma unroll
            for (int c = 0; c < 4; ++c)
                acc = __builtin_amdgcn_mfma_f32_16x16x32_bf16(a[g][c], bc[c], acc, 0, 0, 0);
            __builtin_amdgcn_s_setprio(0);
            if (js == iw + g * 16) {                  // wave-uniform diagonal tile
                #pragma unroll
                for (int r = 0; r < 4; ++r)
                    zacc[g][r] += (col == q * 4 + r) ? 0.0f
                        : __builtin_amdgcn_exp2f(fmaf(acc[r], K2E, -K2E));
            } else {
                #pragma unroll
                for (int r = 0; r < 4; ++r)
                    zacc[g][r] += __builtin_amdgcn_exp2f(fmaf(acc[r], K2E, -K2E));
            }
        }

        #pragma unroll
        for (int c = 0; c < 4; ++c) bc[c] = bn[c];
    }

    // per-row reduce across the 16 cols of each quad; atomic merge of partials
    #pragma unroll
    for (int g = 0; g < 4; ++g)
        #pragma unroll
        for (int r = 0; r < 4; ++r) {
            float zv = zacc[g][r];
            zv += __shfl_xor(zv, 1);
            zv += __shfl_xor(zv, 2);
            zv += __shfl_xor(zv, 4);
            zv += __shfl_xor(zv, 8);
            if (col == 0)
                atomicAdd(&z[iw + g * 16 + q * 4 + r], zv);
        }
}

// Kernel 3: single-block epilogue.
// loss = [ sum_i P_i*(10+ln z_i) - 10*sum_k S[k]^2 + 10*N ] / N
__global__ __launch_bounds__(1024) void final_kernel(
        const int* __restrict__ labels, const int* __restrict__ cnt,
        const float* __restrict__ z, const float* __restrict__ S,
        float* __restrict__ out) {
    __shared__ float part[16];
    const int tid = threadIdx.x;
    float acc = 0.0f;
    #pragma unroll
    for (int k = 0; k < N / 1024; ++k) {
        const int row = k * 1024 + tid;
        const int P = cnt[labels[row]] - 1;
        if (P > 0)
            acc += (float)P * fmaf(LN2, __builtin_amdgcn_logf(z[row]), 10.0f);
    }
    #pragma unroll
    for (int k = 0; k < (NCLS * D + 1023) / 1024; ++k) {
        const int idx = k * 1024 + tid;
        if (idx < NCLS * D) {
            const float sv = S[idx];
            acc -= 10.0f * sv * sv;
        }
    }
    #pragma unroll
    for (int off = 32; off; off >>= 1) acc += __shfl_xor(acc, off);
    if ((tid & 63) == 0) part[tid >> 6] = acc;
    __syncthreads();
    if (tid == 0) {
        float tot = 0.0f;
        #pragma unroll
        for (int w = 0; w < 16; ++w) tot += part[w];
        out[0] = (tot + 10.0f * (float)N) * (1.0f / (float)N);
    }
}

extern "C" void kernel_launch(void* const* d_in, const int* in_sizes, int n_in,
                              void* d_out, int out_size, void* d_ws, size_t ws_size,
                              hipStream_t stream) {
    const float* emb  = (const float*)d_in[0];
    const int* labels = (const int*)d_in[1];
    float* out        = (float*)d_out;
    char* ws          = (char*)d_ws;

    unsigned char* ebf = (unsigned char*)(ws + EBF_OFF);
    float* enorm       = (float*)(ws + ENORM_OFF);
    int*   cnt         = (int*)(ws + CNT_OFF);
    float* z           = (float*)(ws + Z_OFF);
    int*   rowlist     = (int*)(ws + RL_OFF);
    float* S           = (float*)(ws + S_OFF);

    hipMemsetAsync(ws + CNT_OFF, 0, ZERO_SZ, stream);

    prep_kernel<<<N / 4, 256, 0, stream>>>(emb, labels, ebf, cnt, enorm, rowlist);
    zsum_kernel<<<dim3(XGRID, JSPLIT), 256, 0, stream>>>(ebf, z, enorm, cnt, rowlist, S);
    final_kernel<<<1, 1024, 0, stream>>>(labels, cnt, z, S, out);
}

// Round 7
// 125.086 us; speedup vs baseline: 1.9618x; 1.9618x over previous
//
#include <hip/hip_runtime.h>

// ContrastiveLoss on MI355X (gfx950) — round 11
// loss = (1/n) [ sum_i P_i*(10+log z_i) - 10*(sum_c ||S_c||^2 - n) ]
//   z_i = sum_{j != i} exp(10*dot_ij - 10)
// R11: SYMMETRY — each unordered 16x16 tile-pair computed ONCE (circulant
// pairing: i-tile ti handles distances d in [1,255], plus d=256 iff ti<256,
// plus its own diagonal with self-exclusion). Row-sums credit z[i-side];
// column-sums credit z[j-side] via a 1.25KB LDS partial buffer flushed once
// (nonzero-skip). Grid 32x32 m-windows of 8 keeps 1024 blocks = 4/CU
// co-resident (R8 lesson: occupancy beats everything here). NO launch_bounds
// VGPR cap (R10 lesson: a 64-VGPR cap spilled the whole working set).

#define N 8192
#define D 128
#define NCLS 100
#define NTILE 512          // N/16 tiles
#define RLCAP 256          // rowlist slots per class (~82+-9 expected)
#define IBLK 256           // i-rows per block (4 waves x 64 = 16 tiles)
#define MWIN 8             // m-values per window
#define YGRID 32           // m-windows: covers m = 1..256 (+extras 257..259)
#define LDS_TILES 20       // rel = w*4 (<=12) + (m-m_lo) (<=7)
#define K2E 14.4269504088896340736f   // 10*log2(e)
#define LN2 0.69314718055994530942f

typedef __bf16 bf16x8 __attribute__((ext_vector_type(8)));
typedef float f32x4 __attribute__((ext_vector_type(4)));

// ws layout (bytes) — CNT and Z contiguous so one memset zeroes both
#define EBF_OFF  0x000000u  // bf16 E fragment-major: 2 MB
#define ENORM_OFF 0x200000u // fp32 normalized E row-major: 4 MB
#define CNT_OFF  0x600000u  // class counts: 512 B
#define Z_OFF    0x600200u  // z per row: 32 KB
#define RL_OFF   0x608200u  // rowlist: 100*256*4 = 100 KB (gated by cnt)
#define S_OFF    0x621200u  // S_c: 100*128*4 = 50 KB (fully written)
#define ZERO_SZ  (512u + 32768u)

__device__ __forceinline__ unsigned short f32_to_bf16_rne(float f) {
    unsigned int u = __float_as_uint(f);
    u += 0x7fffu + ((u >> 16) & 1u);
    return (unsigned short)(u >> 16);
}

// Fragment-major layout of E (harness-verified):
//   row r: grp=r>>4, col=r&15 ; element k: c=k>>5, q=(k>>3)&3, jj=k&7
//   byte = grp*4096 + c*1024 + q*256 + col*16 + jj*2

// Kernel 1: normalize rows -> fragment-major bf16 E + row-major fp32 enorm;
// class histogram doubles as rowlist slot allocator (1 atomic per row).
__global__ __launch_bounds__(256) void prep_kernel(
        const float* __restrict__ emb, const int* __restrict__ labels,
        unsigned char* __restrict__ ebf, int* __restrict__ cnt,
        float* __restrict__ enorm, int* __restrict__ rowlist) {
    const int wave = threadIdx.x >> 6;
    const int lane = threadIdx.x & 63;
    const int row  = blockIdx.x * 4 + wave;

    const float2 v = *(const float2*)(emb + (size_t)row * D + lane * 2);
    float ss = v.x * v.x + v.y * v.y;
    #pragma unroll
    for (int off = 32; off; off >>= 1) ss += __shfl_xor(ss, off);
    const float inv = 1.0f / fmaxf(sqrtf(ss), 1e-12f);
    const float ex = v.x * inv, ey = v.y * inv;

    const int grp = row >> 4, col = row & 15;
    const int c = lane >> 4, q = (lane >> 2) & 3, j2 = lane & 3;
    unsigned int packed = (unsigned int)f32_to_bf16_rne(ex) |
                          ((unsigned int)f32_to_bf16_rne(ey) << 16);
    *(unsigned int*)(ebf + grp * 4096 + c * 1024 + q * 256 + col * 16 + j2 * 4) = packed;

    float2* ep = (float2*)(enorm + (size_t)row * D + lane * 2);
    *ep = make_float2(ex, ey);

    if (lane == 0) {
        const int lab = labels[row];
        int slot = atomicAdd(&cnt[lab], 1);
        slot = slot < RLCAP ? slot : RLCAP - 1;   // defensive
        rowlist[lab * RLCAP + slot] = row;
    }
}

// Kernel 2: exact fp32 per-class sums via rowlist gather.
__global__ __launch_bounds__(128) void classsum_kernel(
        const float* __restrict__ enorm, const int* __restrict__ cnt,
        const int* __restrict__ rowlist, float* __restrict__ S) {
    const int c = blockIdx.x;
    const int d = threadIdx.x;
    const int n = cnt[c] < RLCAP ? cnt[c] : RLCAP;
    const int* rl = rowlist + c * RLCAP;
    float acc = 0.0f;
    int idx = 0;
    for (; idx + 4 <= n; idx += 4) {
        const int r0 = rl[idx], r1 = rl[idx + 1], r2 = rl[idx + 2], r3 = rl[idx + 3];
        acc += enorm[(size_t)r0 * D + d] + enorm[(size_t)r1 * D + d]
             + enorm[(size_t)r2 * D + d] + enorm[(size_t)r3 * D + d];
    }
    for (; idx < n; ++idx)
        acc += enorm[(size_t)rl[idx] * D + d];
    S[c * D + d] = acc;
}

// Kernel 3: z with symmetry. Wave owns 4 consecutive i-tiles (64 rows).
// Window y processes m in [8y+1, 8y+8] (+1 extra for y in {29,30,31}):
// tj = (ti0+m) mod 512; group g active iff d=m-g in [1,255], or d==256 and
// bi<16 (ties split). Diagonal tiles (d=0) handled by window y==0 only,
// row-sums with self-exclusion. Off-diag tiles credit BOTH sides:
// rows via zacc registers, cols via LDS partials (one flush per block).
__global__ __launch_bounds__(256) void zsum_kernel(
        const unsigned char* __restrict__ ebf, float* __restrict__ z) {
    __shared__ float zcol[LDS_TILES * 16];
    const int t    = threadIdx.x;
    const int w    = t >> 6;
    const int lane = t & 63;
    const int q    = lane >> 4;
    const int col  = lane & 15;
    const int bi   = blockIdx.x;                 // 0..31  i-block
    const int y    = blockIdx.y;                 // 0..31  m-window
    const int ti0  = bi * 16 + w * 4;            // wave's first i-tile
    const int m_lo = y * MWIN + 1;
    const bool lowhalf = (bi < 16);              // ti_g < 256 for all g,w

    for (int e = t; e < LDS_TILES * 16; e += 256) zcol[e] = 0.0f;

    // A fragments: 4 i-tiles x 4 K-chunks, coalesced 1KB loads
    bf16x8 a[4][4];
    #pragma unroll
    for (int g = 0; g < 4; ++g) {
        const unsigned char* ag = ebf + (size_t)(ti0 + g) * 4096 + lane * 16;
        #pragma unroll
        for (int c = 0; c < 4; ++c) a[g][c] = *(const bf16x8*)(ag + c * 1024);
    }

    float zacc[4][4] = {{0.f,0.f,0.f,0.f},{0.f,0.f,0.f,0.f},
                        {0.f,0.f,0.f,0.f},{0.f,0.f,0.f,0.f}};

    __syncthreads();   // zcol zeroed

    // diagonal tiles: window 0 only; full tile, self excluded, row-sums only
    if (y == 0) {
        #pragma unroll
        for (int g = 0; g < 4; ++g) {
            const unsigned char* bg = ebf + (size_t)(ti0 + g) * 4096 + lane * 16;
            bf16x8 bd[4];
            #pragma unroll
            for (int c = 0; c < 4; ++c) bd[c] = *(const bf16x8*)(bg + c * 1024);
            f32x4 acc = {0.f, 0.f, 0.f, 0.f};
            #pragma unroll
            for (int c = 0; c < 4; ++c)
                acc = __builtin_amdgcn_mfma_f32_16x16x32_bf16(a[g][c], bd[c], acc, 0, 0, 0);
            #pragma unroll
            for (int r = 0; r < 4; ++r)
                zacc[g][r] += (col == q * 4 + r) ? 0.0f
                    : __builtin_amdgcn_exp2f(fmaf(acc[r], K2E, -K2E));
        }
    }

    // extra m beyond 256: y=29->257 (g>=2 +cond g=1), y=30->258, y=31->259
    const int ns = MWIN + ((y == 29 || y == 30 || (y == 31 && lowhalf)) ? 1 : 0);
    const int m_x = 228 + y;

    // prologue: load B tile for s=0
    bf16x8 bc[4];
    {
        const int tj = (ti0 + m_lo) & (NTILE - 1);
        const unsigned char* bg = ebf + (size_t)tj * 4096 + lane * 16;
        #pragma unroll
        for (int c = 0; c < 4; ++c) bc[c] = *(const bf16x8*)(bg + c * 1024);
    }

    #pragma unroll 2
    for (int s = 0; s < ns; ++s) {
        const int m = (s < MWIN) ? (m_lo + s) : m_x;

        // prefetch next B tile (last iter reloads current — harmless)
        const int sn = (s + 1 < ns) ? s + 1 : s;
        const int mn = (sn < MWIN) ? (m_lo + sn) : m_x;
        bf16x8 bn[4];
        {
            const int tjn = (ti0 + mn) & (NTILE - 1);
            const unsigned char* bg = ebf + (size_t)tjn * 4096 + lane * 16;
            #pragma unroll
            for (int c = 0; c < 4; ++c) bn[c] = *(const bf16x8*)(bg + c * 1024);
        }

        float ctot = 0.0f;
        #pragma unroll
        for (int g = 0; g < 4; ++g) {
            const int d = m - g;
            const bool act = (d >= 1 && d <= 255) || (d == 256 && lowhalf);
            if (act) {
                f32x4 acc = {0.f, 0.f, 0.f, 0.f};
                __builtin_amdgcn_s_setprio(1);
                #pragma unroll
                for (int c = 0; c < 4; ++c)
                    acc = __builtin_amdgcn_mfma_f32_16x16x32_bf16(a[g][c], bc[c], acc, 0, 0, 0);
                __builtin_amdgcn_s_setprio(0);
                #pragma unroll
                for (int r = 0; r < 4; ++r) {
                    const float p = __builtin_amdgcn_exp2f(fmaf(acc[r], K2E, -K2E));
                    zacc[g][r] += p;
                    ctot += p;
                }
            }
        }

        // column sums -> j-side credit. Reduce across q (rows of tile).
        ctot += __shfl_xor(ctot, 16);
        ctot += __shfl_xor(ctot, 32);
        if (q == 0 && ctot != 0.0f) {
            if (s < MWIN) {
                const int rel = w * 4 + (m - m_lo);          // 0..19
                atomicAdd(&zcol[rel * 16 + col], ctot);
            } else {
                const int tj = (ti0 + m) & (NTILE - 1);
                atomicAdd(&z[tj * 16 + col], ctot);
            }
        }

        #pragma unroll
        for (int c = 0; c < 4; ++c) bc[c] = bn[c];
    }

    // i-side: per-row reduce across the 16 cols of each quad
    #pragma unroll
    for (int g = 0; g < 4; ++g)
        #pragma unroll
        for (int r = 0; r < 4; ++r) {
            float zv = zacc[g][r];
            zv += __shfl_xor(zv, 1);
            zv += __shfl_xor(zv, 2);
            zv += __shfl_xor(zv, 4);
            zv += __shfl_xor(zv, 8);
            if (col == 0)
                atomicAdd(&z[(ti0 + g) * 16 + q * 4 + r], zv);
        }

    // j-side: flush LDS col-partials once
    __syncthreads();
    for (int e = t; e < LDS_TILES * 16; e += 256) {
        const float v = zcol[e];
        if (v != 0.0f) {
            const int tj = (bi * 16 + m_lo + (e >> 4)) & (NTILE - 1);
            atomicAdd(&z[tj * 16 + (e & 15)], v);
        }
    }
}

// Kernel 4: single-block epilogue.
// loss = [ sum_i P_i*(10+ln z_i) - 10*sum_k S[k]^2 + 10*N ] / N
__global__ __launch_bounds__(1024) void final_kernel(
        const int* __restrict__ labels, const int* __restrict__ cnt,
        const float* __restrict__ z, const float* __restrict__ S,
        float* __restrict__ out) {
    __shared__ float part[16];
    const int tid = threadIdx.x;
    float acc = 0.0f;
    #pragma unroll
    for (int k = 0; k < N / 1024; ++k) {
        const int row = k * 1024 + tid;
        const int P = cnt[labels[row]] - 1;
        if (P > 0)
            acc += (float)P * fmaf(LN2, __builtin_amdgcn_logf(z[row]), 10.0f);
    }
    #pragma unroll
    for (int k = 0; k < (NCLS * D + 1023) / 1024; ++k) {
        const int idx = k * 1024 + tid;
        if (idx < NCLS * D) {
            const float sv = S[idx];
            acc -= 10.0f * sv * sv;
        }
    }
    #pragma unroll
    for (int off = 32; off; off >>= 1) acc += __shfl_xor(acc, off);
    if ((tid & 63) == 0) part[tid >> 6] = acc;
    __syncthreads();
    if (tid == 0) {
        float tot = 0.0f;
        #pragma unroll
        for (int w = 0; w < 16; ++w) tot += part[w];
        out[0] = (tot + 10.0f * (float)N) * (1.0f / (float)N);
    }
}

extern "C" void kernel_launch(void* const* d_in, const int* in_sizes, int n_in,
                              void* d_out, int out_size, void* d_ws, size_t ws_size,
                              hipStream_t stream) {
    const float* emb  = (const float*)d_in[0];
    const int* labels = (const int*)d_in[1];
    float* out        = (float*)d_out;
    char* ws          = (char*)d_ws;

    unsigned char* ebf = (unsigned char*)(ws + EBF_OFF);
    float* enorm       = (float*)(ws + ENORM_OFF);
    int*   cnt         = (int*)(ws + CNT_OFF);
    float* z           = (float*)(ws + Z_OFF);
    int*   rowlist     = (int*)(ws + RL_OFF);
    float* S           = (float*)(ws + S_OFF);

    hipMemsetAsync(ws + CNT_OFF, 0, ZERO_SZ, stream);

    prep_kernel<<<N / 4, 256, 0, stream>>>(emb, labels, ebf, cnt, enorm, rowlist);
    classsum_kernel<<<NCLS, 128, 0, stream>>>(enorm, cnt, rowlist, S);
    zsum_kernel<<<dim3(N / IBLK, YGRID), 256, 0, stream>>>(ebf, z);
    final_kernel<<<1, 1024, 0, stream>>>(labels, cnt, z, S, out);
}

// Round 8
// 115.864 us; speedup vs baseline: 2.1179x; 1.0796x over previous
//
#include <hip/hip_runtime.h>

// ContrastiveLoss on MI355X (gfx950) — round 12
// loss = (1/n) [ sum_i P_i*(10+log z_i) - 10*(sum_c ||S_c||^2 - n) ]
//   z_i = sum_{j != i} exp(10*dot_ij - 10)
// R12: dispatch-count reduction. (a) classsum folded into zsum's grid as
// blocks x>=32 (one class per block, 128 threads) — NO VGPR cap this time
// (R10's failure was the __launch_bounds__(256,4) 64-VGPR spill, not the
// fold). (b) prep vectorized to float4 (16B/lane, half-wave per row,
// 8 rows/block, 1024 blocks). zsum math path = R11 verified symmetry
// (circulant tile pairing, row+col credit, LDS col partials).

#define N 8192
#define D 128
#define NCLS 100
#define NTILE 512          // N/16 tiles
#define RLCAP 256          // rowlist slots per class (~82+-9 expected)
#define MWIN 8             // m-values per window
#define YGRID 32           // m-windows: covers m = 1..256 (+extras 257..259)
#define XGRID 36           // 32 zsum i-blocks + 4 cols of classsum blocks
#define LDS_TILES 20       // rel = w*4 (<=12) + (m-m_lo) (<=7)
#define K2E 14.4269504088896340736f   // 10*log2(e)
#define LN2 0.69314718055994530942f

typedef __bf16 bf16x8 __attribute__((ext_vector_type(8)));
typedef float f32x4 __attribute__((ext_vector_type(4)));

// ws layout (bytes) — CNT and Z contiguous so one memset zeroes both
#define EBF_OFF  0x000000u  // bf16 E fragment-major: 2 MB
#define ENORM_OFF 0x200000u // fp32 normalized E row-major: 4 MB
#define CNT_OFF  0x600000u  // class counts: 512 B
#define Z_OFF    0x600200u  // z per row: 32 KB
#define RL_OFF   0x608200u  // rowlist: 100*256*4 = 100 KB (gated by cnt)
#define S_OFF    0x621200u  // S_c: 100*128*4 = 50 KB (fully written)
#define ZERO_SZ  (512u + 32768u)

__device__ __forceinline__ unsigned short f32_to_bf16_rne(float f) {
    unsigned int u = __float_as_uint(f);
    u += 0x7fffu + ((u >> 16) & 1u);
    return (unsigned short)(u >> 16);
}

// Fragment-major layout of E (harness-verified):
//   row r: grp=r>>4, col=r&15 ; element k: c=k>>5, q=(k>>3)&3, jj=k&7
//   byte = grp*4096 + c*1024 + q*256 + col*16 + jj*2
// float4 lane mapping: lane li in [0,32) holds k=4li..4li+3 ->
//   c=li>>3, q=(li>>1)&3, byte base + (li&1)*8, one 8B store.

// Kernel 1: normalize rows -> fragment-major bf16 E + row-major fp32 enorm;
// class histogram doubles as rowlist slot allocator (1 atomic per row).
// Half-wave (32 lanes) per row, float4 loads; 8 rows per block.
__global__ __launch_bounds__(256) void prep_kernel(
        const float* __restrict__ emb, const int* __restrict__ labels,
        unsigned char* __restrict__ ebf, int* __restrict__ cnt,
        float* __restrict__ enorm, int* __restrict__ rowlist) {
    const int w    = threadIdx.x >> 6;
    const int lane = threadIdx.x & 63;
    const int h    = lane >> 5;
    const int li   = lane & 31;
    const int row  = blockIdx.x * 8 + w * 2 + h;

    const float4 v = *(const float4*)(emb + (size_t)row * D + li * 4);
    float ss = v.x * v.x + v.y * v.y + v.z * v.z + v.w * v.w;
    #pragma unroll
    for (int off = 16; off; off >>= 1) ss += __shfl_xor(ss, off);   // within half
    const float inv = 1.0f / fmaxf(sqrtf(ss), 1e-12f);
    const float e0 = v.x * inv, e1 = v.y * inv, e2 = v.z * inv, e3 = v.w * inv;

    const int grp = row >> 4, col = row & 15;
    const int c = li >> 3, q = (li >> 1) & 3, jh = li & 1;
    uint2 packed;
    packed.x = (unsigned)f32_to_bf16_rne(e0) | ((unsigned)f32_to_bf16_rne(e1) << 16);
    packed.y = (unsigned)f32_to_bf16_rne(e2) | ((unsigned)f32_to_bf16_rne(e3) << 16);
    *(uint2*)(ebf + grp * 4096 + c * 1024 + q * 256 + col * 16 + jh * 8) = packed;

    *(float4*)(enorm + (size_t)row * D + li * 4) = make_float4(e0, e1, e2, e3);

    if (li == 0) {
        const int lab = labels[row];
        int slot = atomicAdd(&cnt[lab], 1);
        slot = slot < RLCAP ? slot : RLCAP - 1;   // defensive
        rowlist[lab * RLCAP + slot] = row;
    }
}

// Kernel 2: zsum (blocks x<32) + classsum (blocks x>=32, 1 class each).
// zsum: symmetry via circulant pairing — wave owns 4 consecutive i-tiles;
// window y handles m in [8y+1, 8y+8] (+1 extra for y in {29,30,31});
// group g active iff d=m-g in [1,255], or d==256 for low-half blocks.
// Diagonal tiles: window 0, row-sums with self-exclusion. Off-diag credit
// BOTH sides: rows in registers, cols via LDS partials flushed once.
__global__ __launch_bounds__(256) void zsum_kernel(
        const unsigned char* __restrict__ ebf, float* __restrict__ z,
        const float* __restrict__ enorm, const int* __restrict__ cnt,
        const int* __restrict__ rowlist, float* __restrict__ S) {
    const int t = threadIdx.x;

    if (blockIdx.x >= 32) {
        // ---- classsum path: exact fp32 per-class sums via rowlist gather ----
        const int eidx = (blockIdx.x - 32) * YGRID + blockIdx.y;
        if (eidx >= NCLS || t >= 128) return;
        const int d = t;
        const int n = cnt[eidx] < RLCAP ? cnt[eidx] : RLCAP;
        const int* rl = rowlist + eidx * RLCAP;
        float acc = 0.0f;
        int idx = 0;
        for (; idx + 4 <= n; idx += 4) {
            const int r0 = rl[idx], r1 = rl[idx + 1], r2 = rl[idx + 2], r3 = rl[idx + 3];
            acc += enorm[(size_t)r0 * D + d] + enorm[(size_t)r1 * D + d]
                 + enorm[(size_t)r2 * D + d] + enorm[(size_t)r3 * D + d];
        }
        for (; idx < n; ++idx)
            acc += enorm[(size_t)rl[idx] * D + d];
        S[eidx * D + d] = acc;
        return;
    }

    // ---- zsum path ----
    __shared__ float zcol[LDS_TILES * 16];
    const int w    = t >> 6;
    const int lane = t & 63;
    const int q    = lane >> 4;
    const int col  = lane & 15;
    const int bi   = blockIdx.x;                 // 0..31  i-block
    const int y    = blockIdx.y;                 // 0..31  m-window
    const int ti0  = bi * 16 + w * 4;            // wave's first i-tile
    const int m_lo = y * MWIN + 1;
    const bool lowhalf = (bi < 16);              // ti_g < 256 for all g,w

    for (int e = t; e < LDS_TILES * 16; e += 256) zcol[e] = 0.0f;

    // A fragments: 4 i-tiles x 4 K-chunks, coalesced 1KB loads
    bf16x8 a[4][4];
    #pragma unroll
    for (int g = 0; g < 4; ++g) {
        const unsigned char* ag = ebf + (size_t)(ti0 + g) * 4096 + lane * 16;
        #pragma unroll
        for (int c = 0; c < 4; ++c) a[g][c] = *(const bf16x8*)(ag + c * 1024);
    }

    float zacc[4][4] = {{0.f,0.f,0.f,0.f},{0.f,0.f,0.f,0.f},
                        {0.f,0.f,0.f,0.f},{0.f,0.f,0.f,0.f}};

    __syncthreads();   // zcol zeroed

    // diagonal tiles: window 0 only; full tile, self excluded, row-sums only
    if (y == 0) {
        #pragma unroll
        for (int g = 0; g < 4; ++g) {
            const unsigned char* bg = ebf + (size_t)(ti0 + g) * 4096 + lane * 16;
            bf16x8 bd[4];
            #pragma unroll
            for (int c = 0; c < 4; ++c) bd[c] = *(const bf16x8*)(bg + c * 1024);
            f32x4 acc = {0.f, 0.f, 0.f, 0.f};
            #pragma unroll
            for (int c = 0; c < 4; ++c)
                acc = __builtin_amdgcn_mfma_f32_16x16x32_bf16(a[g][c], bd[c], acc, 0, 0, 0);
            #pragma unroll
            for (int r = 0; r < 4; ++r)
                zacc[g][r] += (col == q * 4 + r) ? 0.0f
                    : __builtin_amdgcn_exp2f(fmaf(acc[r], K2E, -K2E));
        }
    }

    // extra m beyond 256: y=29->257, y=30->258, y=31->259 (act filters by d)
    const int ns = MWIN + ((y == 29 || y == 30 || (y == 31 && lowhalf)) ? 1 : 0);
    const int m_x = 228 + y;

    // prologue: load B tile for s=0
    bf16x8 bc[4];
    {
        const int tj = (ti0 + m_lo) & (NTILE - 1);
        const unsigned char* bg = ebf + (size_t)tj * 4096 + lane * 16;
        #pragma unroll
        for (int c = 0; c < 4; ++c) bc[c] = *(const bf16x8*)(bg + c * 1024);
    }

    #pragma unroll 2
    for (int s = 0; s < ns; ++s) {
        const int m = (s < MWIN) ? (m_lo + s) : m_x;

        // prefetch next B tile (last iter reloads current — harmless)
        const int sn = (s + 1 < ns) ? s + 1 : s;
        const int mn = (sn < MWIN) ? (m_lo + sn) : m_x;
        bf16x8 bn[4];
        {
            const int tjn = (ti0 + mn) & (NTILE - 1);
            const unsigned char* bg = ebf + (size_t)tjn * 4096 + lane * 16;
            #pragma unroll
            for (int c = 0; c < 4; ++c) bn[c] = *(const bf16x8*)(bg + c * 1024);
        }

        float ctot = 0.0f;
        #pragma unroll
        for (int g = 0; g < 4; ++g) {
            const int d = m - g;
            const bool act = (d >= 1 && d <= 255) || (d == 256 && lowhalf);
            if (act) {
                f32x4 acc = {0.f, 0.f, 0.f, 0.f};
                __builtin_amdgcn_s_setprio(1);
                #pragma unroll
                for (int c = 0; c < 4; ++c)
                    acc = __builtin_amdgcn_mfma_f32_16x16x32_bf16(a[g][c], bc[c], acc, 0, 0, 0);
                __builtin_amdgcn_s_setprio(0);
                #pragma unroll
                for (int r = 0; r < 4; ++r) {
                    const float p = __builtin_amdgcn_exp2f(fmaf(acc[r], K2E, -K2E));
                    zacc[g][r] += p;
                    ctot += p;
                }
            }
        }

        // column sums -> j-side credit. Reduce across q (rows of tile).
        ctot += __shfl_xor(ctot, 16);
        ctot += __shfl_xor(ctot, 32);
        if (q == 0 && ctot != 0.0f) {
            if (s < MWIN) {
                const int rel = w * 4 + (m - m_lo);          // 0..19
                atomicAdd(&zcol[rel * 16 + col], ctot);
            } else {
                const int tj = (ti0 + m) & (NTILE - 1);
                atomicAdd(&z[tj * 16 + col], ctot);
            }
        }

        #pragma unroll
        for (int c = 0; c < 4; ++c) bc[c] = bn[c];
    }

    // i-side: per-row reduce across the 16 cols of each quad
    #pragma unroll
    for (int g = 0; g < 4; ++g)
        #pragma unroll
        for (int r = 0; r < 4; ++r) {
            float zv = zacc[g][r];
            zv += __shfl_xor(zv, 1);
            zv += __shfl_xor(zv, 2);
            zv += __shfl_xor(zv, 4);
            zv += __shfl_xor(zv, 8);
            if (col == 0)
                atomicAdd(&z[(ti0 + g) * 16 + q * 4 + r], zv);
        }

    // j-side: flush LDS col-partials once
    __syncthreads();
    for (int e = t; e < LDS_TILES * 16; e += 256) {
        const float v = zcol[e];
        if (v != 0.0f) {
            const int tj = (bi * 16 + m_lo + (e >> 4)) & (NTILE - 1);
            atomicAdd(&z[tj * 16 + (e & 15)], v);
        }
    }
}

// Kernel 3: single-block epilogue.
// loss = [ sum_i P_i*(10+ln z_i) - 10*sum_k S[k]^2 + 10*N ] / N
__global__ __launch_bounds__(1024) void final_kernel(
        const int* __restrict__ labels, const int* __restrict__ cnt,
        const float* __restrict__ z, const float* __restrict__ S,
        float* __restrict__ out) {
    __shared__ float part[16];
    const int tid = threadIdx.x;
    float acc = 0.0f;
    #pragma unroll
    for (int k = 0; k < N / 1024; ++k) {
        const int row = k * 1024 + tid;
        const int P = cnt[labels[row]] - 1;
        if (P > 0)
            acc += (float)P * fmaf(LN2, __builtin_amdgcn_logf(z[row]), 10.0f);
    }
    #pragma unroll
    for (int k = 0; k < (NCLS * D + 1023) / 1024; ++k) {
        const int idx = k * 1024 + tid;
        if (idx < NCLS * D) {
            const float sv = S[idx];
            acc -= 10.0f * sv * sv;
        }
    }
    #pragma unroll
    for (int off = 32; off; off >>= 1) acc += __shfl_xor(acc, off);
    if ((tid & 63) == 0) part[tid >> 6] = acc;
    __syncthreads();
    if (tid == 0) {
        float tot = 0.0f;
        #pragma unroll
        for (int w = 0; w < 16; ++w) tot += part[w];
        out[0] = (tot + 10.0f * (float)N) * (1.0f / (float)N);
    }
}

extern "C" void kernel_launch(void* const* d_in, const int* in_sizes, int n_in,
                              void* d_out, int out_size, void* d_ws, size_t ws_size,
                              hipStream_t stream) {
    const float* emb  = (const float*)d_in[0];
    const int* labels = (const int*)d_in[1];
    float* out        = (float*)d_out;
    char* ws          = (char*)d_ws;

    unsigned char* ebf = (unsigned char*)(ws + EBF_OFF);
    float* enorm       = (float*)(ws + ENORM_OFF);
    int*   cnt         = (int*)(ws + CNT_OFF);
    float* z           = (float*)(ws + Z_OFF);
    int*   rowlist     = (int*)(ws + RL_OFF);
    float* S           = (float*)(ws + S_OFF);

    hipMemsetAsync(ws + CNT_OFF, 0, ZERO_SZ, stream);

    prep_kernel<<<N / 8, 256, 0, stream>>>(emb, labels, ebf, cnt, enorm, rowlist);
    zsum_kernel<<<dim3(XGRID, YGRID), 256, 0, stream>>>(ebf, z, enorm, cnt, rowlist, S);
    final_kernel<<<1, 1024, 0, stream>>>(labels, cnt, z, S, out);
}